// Round 10
// baseline (436.118 us; speedup 1.0000x reference)
//
#include <hip/hip_runtime.h>

// Problem constants
#define Hn  16
#define Dh  64
#define Bb  4
#define Tn  2048
#define En  1024
#define Mn  8192           // B*T
#define N1  3072           // 3*E
#define Kn  1024           // E
#define BHT (Bb*Hn*Tn)     // 262144

typedef __attribute__((ext_vector_type(8)))  short  short8;
typedef __attribute__((ext_vector_type(4)))  short  short4v;
typedef __attribute__((ext_vector_type(4)))  float  f32x4;
typedef __attribute__((ext_vector_type(8)))  __bf16 bf16x8;

__device__ __forceinline__ float b2f(short s) {
  unsigned u = ((unsigned)(unsigned short)s) << 16;
  return __builtin_bit_cast(float, u);
}
__device__ __forceinline__ short f2b(float f) {
  unsigned u = __builtin_bit_cast(unsigned, f);
  u += 0x7fffu + ((u >> 16) & 1u);
  return (short)(u >> 16);
}
__device__ __forceinline__ f32x4 mfma16(short8 a, short8 b, f32x4 c) {
  return __builtin_amdgcn_mfma_f32_16x16x32_bf16(
      __builtin_bit_cast(bf16x8, a), __builtin_bit_cast(bf16x8, b), c, 0, 0, 0);
}
__device__ __forceinline__ void gload16(const void* g, void* l) {
  __builtin_amdgcn_global_load_lds(
      (const __attribute__((address_space(1))) unsigned int*)g,
      (__attribute__((address_space(3))) unsigned int*)l, 16, 0, 0);
}

// ---------------- cast x -> bf16 ----------------
__global__ __launch_bounds__(256) void cvt_x_kernel(const float* __restrict__ x,
                                                    short* __restrict__ xb) {
  const size_t i = ((size_t)blockIdx.x * 256 + threadIdx.x) * 8;
  f32x4 a = *(const f32x4*)&x[i];
  f32x4 b = *(const f32x4*)&x[i + 4];
  short8 o;
  o[0]=f2b(a[0]); o[1]=f2b(a[1]); o[2]=f2b(a[2]); o[3]=f2b(a[3]);
  o[4]=f2b(b[0]); o[5]=f2b(b[1]); o[6]=f2b(b[2]); o[7]=f2b(b[3]);
  *(short8*)&xb[i] = o;
}

// ---------------- transpose W [R][C] f32 -> [C][R] bf16 ----------------
__global__ __launch_bounds__(256) void transpose_w_kernel(const float* __restrict__ in,
                                                          short* __restrict__ out,
                                                          int R, int C) {
  __shared__ float tile[32][33];
  const int tid = threadIdx.x;
  const int c0 = blockIdx.x * 32, r0 = blockIdx.y * 32;
  const int lr = tid >> 3, lc = (tid & 7) * 4;
  f32x4 v = *(const f32x4*)&in[(size_t)(r0 + lr) * C + c0 + lc];
  tile[lr][lc] = v[0]; tile[lr][lc+1] = v[1]; tile[lr][lc+2] = v[2]; tile[lr][lc+3] = v[3];
  __syncthreads();
  const int oc = tid >> 3, orr = (tid & 7) * 4;
  short4v ov;
  ov[0] = f2b(tile[orr][oc]);   ov[1] = f2b(tile[orr+1][oc]);
  ov[2] = f2b(tile[orr+2][oc]); ov[3] = f2b(tile[orr+3][oc]);
  *(short4v*)&out[(size_t)(c0 + oc) * R + r0 + orr] = ov;
}

// ---------------- GEMM: C[M][N] = A[M][K] * Bt[N][K]^T + bias ----------------
// 1-D grid, bijective XCD swizzle. 2-phase double-buffered staging: one
// barrier per K-step, DMA of tile t+1 overlaps MFMA of tile t (T3-minimal).
// MODE 1: fused bias + q/k LayerNorm (q scaled 0.125*log2e) + transposed V.
template<int MODE>
__global__ __launch_bounds__(256) void gemm_kernel(
    const short* __restrict__ A, const short* __restrict__ Bt,
    const float* __restrict__ bias, float* __restrict__ Cf,
    short* __restrict__ qo, short* __restrict__ ko2, short* __restrict__ vo,
    const float* __restrict__ qg, const float* __restrict__ qb,
    const float* __restrict__ kg, const float* __restrict__ kb,
    int N, int NBX, int cpx) {
  __shared__ short As[2][4096];
  __shared__ short Bs[2][4096];
  const int lin = blockIdx.x;
  const int swz = (lin & 7) * cpx + (lin >> 3);
  const int bx = swz % NBX, by = swz / NBX;
  const int tid = threadIdx.x, lane = tid & 63, w = tid >> 6;
  const int rowBase = by * 128, colBase = bx * 128;
  f32x4 acc[4][4] = {};
  const int srow = tid >> 2, sk = (tid & 3) << 3;
  const short* Ag = A  + (size_t)(rowBase + srow) * Kn + sk;
  const short* Bg = Bt + (size_t)(colBase + srow) * Kn + sk;
  const int ar = (w >> 1) * 64, bc = (w & 1) * 64;
  const int lg8 = (lane >> 4) * 8, lr = lane & 15;

#define GSTAGE(kt, b)                                    \
  {                                                      \
    gload16(Ag + (kt),           &As[b][w * 512]);       \
    gload16(Ag + (kt) + 64 * Kn, &As[b][w * 512 + 2048]);\
    gload16(Bg + (kt),           &Bs[b][w * 512]);       \
    gload16(Bg + (kt) + 64 * Kn, &Bs[b][w * 512 + 2048]);\
  }

  GSTAGE(0, 0);
  __syncthreads();

  for (int it = 0; it < Kn / 32; ++it) {
    const int cur = it & 1;
    if (it + 1 < Kn / 32) GSTAGE((it + 1) * 32, cur ^ 1);
    short8 af[4], bfr[4];
#pragma unroll
    for (int m = 0; m < 4; ++m) af[m]  = *(const short8*)&As[cur][(ar + m*16 + lr)*32 + lg8];
#pragma unroll
    for (int n = 0; n < 4; ++n) bfr[n] = *(const short8*)&Bs[cur][(bc + n*16 + lr)*32 + lg8];
#pragma unroll
    for (int m = 0; m < 4; ++m)
#pragma unroll
      for (int n = 0; n < 4; ++n)
        acc[m][n] = mfma16(af[m], bfr[n], acc[m][n]);
    __syncthreads();   // drains vmcnt (next tile staged) + all waves done with cur
  }
#undef GSTAGE

  const int gr0 = rowBase + ar + (lane >> 4) * 4;
  const int gc0 = colBase + bc + lr;

  float bb[4];
#pragma unroll
  for (int n = 0; n < 4; ++n) bb[n] = bias[gc0 + n * 16];
#pragma unroll
  for (int m = 0; m < 4; ++m)
#pragma unroll
    for (int n = 0; n < 4; ++n)
#pragma unroll
      for (int r = 0; r < 4; ++r) acc[m][n][r] += bb[n];

  if (MODE == 1) {
    const int which = colBase >> 10;            // block-uniform: 0=q 1=k 2=v
    if (which < 2) {
      const float* gp = (which == 0) ? qg : kg;
      const float* bp = (which == 0) ? qb : kb;
      const float sc = (which == 0) ? 0.1803368801111204f : 1.0f;  // 0.125*log2(e)
      float gam[4], bet[4];
#pragma unroll
      for (int n = 0; n < 4; ++n) { gam[n] = gp[n * 16 + lr]; bet[n] = bp[n * 16 + lr]; }
#pragma unroll
      for (int m = 0; m < 4; ++m)
#pragma unroll
        for (int r = 0; r < 4; ++r) {
          float s1 = 0.f, s2 = 0.f;
#pragma unroll
          for (int n = 0; n < 4; ++n) {
            const float v = acc[m][n][r];
            s1 += v; s2 += v * v;
          }
#pragma unroll
          for (int off = 1; off < 16; off <<= 1) {
            s1 += __shfl_xor(s1, off);
            s2 += __shfl_xor(s2, off);
          }
          const float mu = s1 * 0.015625f;
          const float rs = rsqrtf(s2 * 0.015625f - mu * mu + 1e-5f);
#pragma unroll
          for (int n = 0; n < 4; ++n)
            acc[m][n][r] = ((acc[m][n][r] - mu) * rs * gam[n] + bet[n]) * sc;
        }
    }
  }

#pragma unroll
  for (int m = 0; m < 4; ++m) {
#pragma unroll
    for (int n = 0; n < 4; ++n) {
      const int gc = gc0 + n * 16;
#pragma unroll
      for (int r = 0; r < 4; ++r) {
        const int gr = gr0 + m * 16 + r;
        const float v = acc[m][n][r];
        if (MODE == 0) {
          Cf[(size_t)gr * N + gc] = v;
        } else {
          const int which = gc >> 10, e = gc & 1023;
          const int hh = e >> 6, d = e & 63;
          const int bidx = gr >> 11, t = gr & 2047;
          const int bh = bidx * Hn + hh;
          if (which == 0) {
            qo[((size_t)bh * Tn + t) * Dh + d] = f2b(v);
          } else if (which == 1) {
            ko2[((size_t)bh * Tn + t) * Dh + d] = f2b(v);
          } else {
            vo[((size_t)bh * Dh + d) * Tn + t] = f2b(v);   // transposed [bh][d][t]
          }
        }
      }
    }
  }
}

// ---------------- Flash attention (round-8 structure; V direct from global) ----------------
// 1024 blocks (XCD-swizzled), 4 waves, 32 q-rows/wave, KVBLK=64.
// K staged via dbuf LDS (gload16, swizzled); V fragments loaded straight from
// global [bh][d][t] as 16B dwordx4 (L2-resident; 16 blocks/bh per XCD) -> Vs
// LDS buffer and its 8 b128 reads/tile removed (DS-pipe was the hot resource).
// bv loads issued BEFORE the K-STAGE so their s_waitcnt is vmcnt(2), keeping
// the K prefetch in flight. Softmax path identical to round 8.
__global__ __launch_bounds__(256) void flash_kernel(
    const short* __restrict__ qp, const short* __restrict__ kp,
    const short* __restrict__ vt, short* __restrict__ y) {
  __shared__ short Ks[2][4096];   // [buf][64 keys][64 d]
  __shared__ short Ps[4096];      // per-wave 1024 shorts: [32 q][32 k] half-tile
  const int tid = threadIdx.x, lane = tid & 63, w = tid >> 6;
  const int lr = lane & 15, lg = lane >> 4;

  // XCD swizzle (bijective): XCD x handles bh in [8x,8x+8), 16 q-tiles each
  const int j0 = blockIdx.x;
  const int xcd = j0 & 7, kk0 = j0 >> 3;
  const int bh = 8 * xcd + (kk0 & 7), qt = kk0 >> 3;

  const int qrow0 = qt * 128 + w * 32;
  const short* qbase = qp + ((size_t)bh * Tn + qrow0) * Dh;

  short8 aq[2][2];
#pragma unroll
  for (int m = 0; m < 2; ++m)
#pragma unroll
    for (int kk = 0; kk < 2; ++kk)
      aq[m][kk] = *(const short8*)&qbase[(m*16 + lr)*64 + kk*32 + lg*8];

  short8 ones;
#pragma unroll
  for (int i = 0; i < 8; ++i) ones[i] = (short)0x3F80;   // bf16 1.0

  f32x4 o[2][4] = {};
  f32x4 lacc[2] = {};             // row sums via ones-MFMA
  float mrow[2][4];
#pragma unroll
  for (int m = 0; m < 2; ++m)
#pragma unroll
    for (int r = 0; r < 4; ++r) mrow[m][r] = -3e38f;

  const int srow = tid >> 3;         // 0..31
  const int sc = (tid & 7) * 8;      // shorts
  short* Pw = Ps + w * 1024;
  const short* kb = kp + (size_t)bh * Tn * Dh;
  const short* vb = vt + (size_t)bh * Dh * Tn;

#define STAGE(jt, bsel)                                                   \
  {                                                                       \
    _Pragma("unroll")                                                     \
    for (int i = 0; i < 2; ++i) {                                         \
      const int row = i * 32 + srow;                                      \
      const int scs = sc ^ ((row & 7) << 3);                              \
      gload16(kb + (size_t)((jt) * 64 + row) * Dh + scs,                  \
              &Ks[bsel][w * 512 + i * 2048]);                             \
    }                                                                     \
  }

// P swizzle: 8-short granular, bijective within a 32-short row
#define PSW(q) ((((q) & 3) << 3) ^ (((q) & 4) << 2))

  STAGE(0, 0);
  __syncthreads();

  for (int j = 0; j < Tn / 64; ++j) {
    const int cur = j & 1;

    // V fragments direct from global (issued FIRST: consuming them later
    // waits vmcnt(2), leaving the K-stage below in flight)
    const short* vbj = vb + j * 64;
    short8 bv[4][2];
#pragma unroll
    for (int dn = 0; dn < 4; ++dn)
#pragma unroll
      for (int kk = 0; kk < 2; ++kk)
        bv[dn][kk] = *(const short8*)&vbj[(size_t)(dn*16 + lr) * Tn + kk*32 + lg*8];

    if (j + 1 < Tn / 64) STAGE(j + 1, cur ^ 1);

    // S = Q K^T  (C: row=q=lg*4+r+16m, col=key=lr+16n)
    short8 bk[4][2];
#pragma unroll
    for (int n = 0; n < 4; ++n)
#pragma unroll
      for (int kk = 0; kk < 2; ++kk) {
        const int row = n * 16 + lr;
        bk[n][kk] = *(const short8*)&Ks[cur][row*64 + ((kk*32 + lg*8) ^ ((row & 7) << 3))];
      }
    f32x4 s[2][4] = {};
    __builtin_amdgcn_s_setprio(1);
#pragma unroll
    for (int m = 0; m < 2; ++m)
#pragma unroll
      for (int n = 0; n < 4; ++n) {
        s[m][n] = mfma16(aq[m][0], bk[n][0], s[m][n]);
        s[m][n] = mfma16(aq[m][1], bk[n][1], s[m][n]);
      }
    __builtin_amdgcn_s_setprio(0);

    // defer-max: per-lane partial max vs stale row max
    float pm[2][4];
#pragma unroll
    for (int m = 0; m < 2; ++m)
#pragma unroll
      for (int r = 0; r < 4; ++r)
        pm[m][r] = fmaxf(fmaxf(s[m][0][r], s[m][1][r]), fmaxf(s[m][2][r], s[m][3][r]));
    int ok = 1;
#pragma unroll
    for (int m = 0; m < 2; ++m)
#pragma unroll
      for (int r = 0; r < 4; ++r)
        ok &= (pm[m][r] <= mrow[m][r] + 11.0f) ? 1 : 0;
    if (!__all(ok)) {
      float tm[2][4];
#pragma unroll
      for (int m = 0; m < 2; ++m)
#pragma unroll
        for (int r = 0; r < 4; ++r) tm[m][r] = pm[m][r];
#pragma unroll
      for (int off = 1; off < 16; off <<= 1)
#pragma unroll
        for (int m = 0; m < 2; ++m)
#pragma unroll
          for (int r = 0; r < 4; ++r)
            tm[m][r] = fmaxf(tm[m][r], __shfl_xor(tm[m][r], off));
#pragma unroll
      for (int m = 0; m < 2; ++m)
#pragma unroll
        for (int r = 0; r < 4; ++r) {
          const float mn = fmaxf(mrow[m][r], tm[m][r]);
          const float corr = __builtin_amdgcn_exp2f(mrow[m][r] - mn);
          lacc[m][r] *= corr;
#pragma unroll
          for (int dn = 0; dn < 4; ++dn) o[m][dn][r] *= corr;
          mrow[m][r] = mn;
        }
    }

    // ---- phase 0: keys 0..31 (n=0,1) ----
#pragma unroll
    for (int m = 0; m < 2; ++m)
#pragma unroll
      for (int n = 0; n < 2; ++n)
#pragma unroll
        for (int r = 0; r < 4; ++r) {
          const float p = __builtin_amdgcn_exp2f(s[m][n][r] - mrow[m][r]);
          const unsigned u = __builtin_bit_cast(unsigned, p);
          const int q = m*16 + lg*4 + r;
          Pw[q*32 + ((n*16 + lr) ^ PSW(q))] = (short)(u >> 16);
        }
    short8 pa0[2];
#pragma unroll
    for (int m = 0; m < 2; ++m) {
      const int q = m*16 + lr;
      pa0[m] = *(const short8*)&Pw[q*32 + ((lg*8) ^ PSW(q))];
    }
    __builtin_amdgcn_s_setprio(1);
#pragma unroll
    for (int m = 0; m < 2; ++m) {
      lacc[m] = mfma16(pa0[m], ones, lacc[m]);
#pragma unroll
      for (int dn = 0; dn < 4; ++dn)
        o[m][dn] = mfma16(pa0[m], bv[dn][0], o[m][dn]);
    }
    __builtin_amdgcn_s_setprio(0);

    // ---- phase 1: keys 32..63 (n=2,3), same buffer (in-order DS) ----
#pragma unroll
    for (int m = 0; m < 2; ++m)
#pragma unroll
      for (int n = 0; n < 2; ++n)
#pragma unroll
        for (int r = 0; r < 4; ++r) {
          const float p = __builtin_amdgcn_exp2f(s[m][2 + n][r] - mrow[m][r]);
          const unsigned u = __builtin_bit_cast(unsigned, p);
          const int q = m*16 + lg*4 + r;
          Pw[q*32 + ((n*16 + lr) ^ PSW(q))] = (short)(u >> 16);
        }
    short8 pa1[2];
#pragma unroll
    for (int m = 0; m < 2; ++m) {
      const int q = m*16 + lr;
      pa1[m] = *(const short8*)&Pw[q*32 + ((lg*8) ^ PSW(q))];
    }
    __builtin_amdgcn_s_setprio(1);
#pragma unroll
    for (int m = 0; m < 2; ++m) {
      lacc[m] = mfma16(pa1[m], ones, lacc[m]);
#pragma unroll
      for (int dn = 0; dn < 4; ++dn)
        o[m][dn] = mfma16(pa1[m], bv[dn][1], o[m][dn]);
    }
    __builtin_amdgcn_s_setprio(0);

    __syncthreads();
  }
#undef STAGE
#undef PSW

  // normalize + store y[B][T][E] bf16
  const int b = bh >> 4, hh = bh & 15;
  short* yb = y + (size_t)b * Tn * En + hh * 64;
#pragma unroll
  for (int m = 0; m < 2; ++m)
#pragma unroll
    for (int r = 0; r < 4; ++r) {
      const float rl = 1.0f / lacc[m][r];
      const int t = qrow0 + m*16 + lg*4 + r;
#pragma unroll
      for (int dn = 0; dn < 4; ++dn) {
        const int d = dn*16 + lr;
        yb[(size_t)t * En + d] = f2b(o[m][dn][r] * rl);
      }
    }
}

extern "C" void kernel_launch(void* const* d_in, const int* in_sizes, int n_in,
                              void* d_out, int out_size, void* d_ws, size_t ws_size,
                              hipStream_t stream) {
  const float* x     = (const float*)d_in[0];
  const float* Wqkv  = (const float*)d_in[1];
  const float* bqkv  = (const float*)d_in[2];
  const float* qg    = (const float*)d_in[3];
  const float* qb    = (const float*)d_in[4];
  const float* kg    = (const float*)d_in[5];
  const float* kb    = (const float*)d_in[6];
  const float* Wproj = (const float*)d_in[7];
  const float* bproj = (const float*)d_in[8];
  float* out = (float*)d_out;

  char* p = (char*)d_ws;
  short* xb     = (short*)p; p += (size_t)Mn * Kn * 2;
  short* wqkvT  = (short*)p; p += (size_t)N1 * Kn * 2;
  short* wprojT = (short*)p; p += (size_t)En * Kn * 2;
  short* qp     = (short*)p; p += (size_t)Mn * Kn * 2;
  short* kp     = (short*)p; p += (size_t)Mn * Kn * 2;
  short* vtb    = (short*)p; p += (size_t)Mn * Kn * 2;
  short* yb     = (short*)p; p += (size_t)Mn * Kn * 2;

  cvt_x_kernel<<<Mn * Kn / (256 * 8), 256, 0, stream>>>(x, xb);
  transpose_w_kernel<<<dim3(N1 / 32, Kn / 32), 256, 0, stream>>>(Wqkv, wqkvT, Kn, N1);
  transpose_w_kernel<<<dim3(En / 32, Kn / 32), 256, 0, stream>>>(Wproj, wprojT, Kn, En);
  gemm_kernel<1><<<(N1 / 128) * (Mn / 128), 256, 0, stream>>>(
      xb, wqkvT, bqkv, nullptr, qp, kp, vtb, qg, qb, kg, kb,
      N1, N1 / 128, (N1 / 128) * (Mn / 128) / 8);
  flash_kernel<<<1024, 256, 0, stream>>>(qp, kp, vtb, yb);
  gemm_kernel<0><<<(En / 128) * (Mn / 128), 256, 0, stream>>>(
      yb, wprojT, bproj, out, nullptr, nullptr, nullptr, nullptr, nullptr, nullptr, nullptr,
      En, En / 128, (En / 128) * (Mn / 128) / 8);
}

// Round 12
// 264.525 us; speedup vs baseline: 1.6487x; 1.6487x over previous
//
#include <hip/hip_runtime.h>

// Problem constants
#define Hn  16
#define Dh  64
#define Bb  4
#define Tn  2048
#define En  1024
#define Mn  8192           // B*T
#define N1  3072           // 3*E
#define Kn  1024           // E

typedef __attribute__((ext_vector_type(8)))  short  short8;
typedef __attribute__((ext_vector_type(4)))  short  short4v;
typedef __attribute__((ext_vector_type(4)))  float  f32x4;
typedef __attribute__((ext_vector_type(8)))  __bf16 bf16x8;

__device__ __forceinline__ float b2f(short s) {
  unsigned u = ((unsigned)(unsigned short)s) << 16;
  return __builtin_bit_cast(float, u);
}
__device__ __forceinline__ short f2b(float f) {
  unsigned u = __builtin_bit_cast(unsigned, f);
  u += 0x7fffu + ((u >> 16) & 1u);
  return (short)(u >> 16);
}
__device__ __forceinline__ f32x4 mfma16(short8 a, short8 b, f32x4 c) {
  return __builtin_amdgcn_mfma_f32_16x16x32_bf16(
      __builtin_bit_cast(bf16x8, a), __builtin_bit_cast(bf16x8, b), c, 0, 0, 0);
}
__device__ __forceinline__ void gload16(const void* g, void* l) {
  __builtin_amdgcn_global_load_lds(
      (const __attribute__((address_space(1))) unsigned int*)g,
      (__attribute__((address_space(3))) unsigned int*)l, 16, 0, 0);
}

// ---------------- cast x -> bf16 ----------------
__global__ __launch_bounds__(256) void cvt_x_kernel(const float* __restrict__ x,
                                                    short* __restrict__ xb) {
  const size_t i = ((size_t)blockIdx.x * 256 + threadIdx.x) * 8;
  f32x4 a = *(const f32x4*)&x[i];
  f32x4 b = *(const f32x4*)&x[i + 4];
  short8 o;
  o[0]=f2b(a[0]); o[1]=f2b(a[1]); o[2]=f2b(a[2]); o[3]=f2b(a[3]);
  o[4]=f2b(b[0]); o[5]=f2b(b[1]); o[6]=f2b(b[2]); o[7]=f2b(b[3]);
  *(short8*)&xb[i] = o;
}

// ---------------- transpose W [R][C] f32 -> [C][R] bf16 ----------------
__global__ __launch_bounds__(256) void transpose_w_kernel(const float* __restrict__ in,
                                                          short* __restrict__ out,
                                                          int R, int C) {
  __shared__ float tile[32][33];
  const int tid = threadIdx.x;
  const int c0 = blockIdx.x * 32, r0 = blockIdx.y * 32;
  const int lr = tid >> 3, lc = (tid & 7) * 4;
  f32x4 v = *(const f32x4*)&in[(size_t)(r0 + lr) * C + c0 + lc];
  tile[lr][lc] = v[0]; tile[lr][lc+1] = v[1]; tile[lr][lc+2] = v[2]; tile[lr][lc+3] = v[3];
  __syncthreads();
  const int oc = tid >> 3, orr = (tid & 7) * 4;
  short4v ov;
  ov[0] = f2b(tile[orr][oc]);   ov[1] = f2b(tile[orr+1][oc]);
  ov[2] = f2b(tile[orr+2][oc]); ov[3] = f2b(tile[orr+3][oc]);
  *(short4v*)&out[(size_t)(c0 + oc) * R + r0 + orr] = ov;
}

// ---------------- GEMM: C[M][N] = A[M][K] * Bt[N][K]^T + bias ----------------
// 1-D grid, bijective XCD swizzle. MODE 1: fused bias + q/k LayerNorm
// (q scaled by 0.125*log2e) + transposed V write. MODE 0: fp32 out + bias.
template<int MODE>
__global__ __launch_bounds__(256) void gemm_kernel(
    const short* __restrict__ A, const short* __restrict__ Bt,
    const float* __restrict__ bias, float* __restrict__ Cf,
    short* __restrict__ qo, short* __restrict__ ko2, short* __restrict__ vo,
    const float* __restrict__ qg, const float* __restrict__ qb,
    const float* __restrict__ kg, const float* __restrict__ kb,
    int N, int NBX, int cpx) {
  __shared__ short As[4096];
  __shared__ short Bs[4096];
  const int lin = blockIdx.x;
  const int swz = (lin & 7) * cpx + (lin >> 3);
  const int bx = swz % NBX, by = swz / NBX;
  const int tid = threadIdx.x, lane = tid & 63, w = tid >> 6;
  const int rowBase = by * 128, colBase = bx * 128;
  f32x4 acc[4][4] = {};
  const int srow = tid >> 2, sk = (tid & 3) << 3;
  const short* Ag = A  + (size_t)(rowBase + srow) * Kn + sk;
  const short* Bg = Bt + (size_t)(colBase + srow) * Kn + sk;
  short* AsW = As + w * 512;
  short* BsW = Bs + w * 512;
  const int ar = (w >> 1) * 64, bc = (w & 1) * 64;
  const int lg8 = (lane >> 4) * 8, lr = lane & 15;

  for (int kt = 0; kt < Kn; kt += 32) {
    __syncthreads();
    gload16(Ag + kt,            AsW);
    gload16(Ag + kt + 64 * Kn,  AsW + 2048);
    gload16(Bg + kt,            BsW);
    gload16(Bg + kt + 64 * Kn,  BsW + 2048);
    __syncthreads();
    short8 af[4], bfr[4];
#pragma unroll
    for (int m = 0; m < 4; ++m) af[m]  = *(const short8*)&As[(ar + m*16 + lr)*32 + lg8];
#pragma unroll
    for (int n = 0; n < 4; ++n) bfr[n] = *(const short8*)&Bs[(bc + n*16 + lr)*32 + lg8];
#pragma unroll
    for (int m = 0; m < 4; ++m)
#pragma unroll
      for (int n = 0; n < 4; ++n)
        acc[m][n] = mfma16(af[m], bfr[n], acc[m][n]);
  }

  const int gr0 = rowBase + ar + (lane >> 4) * 4;
  const int gc0 = colBase + bc + lr;

  float bb[4];
#pragma unroll
  for (int n = 0; n < 4; ++n) bb[n] = bias[gc0 + n * 16];
#pragma unroll
  for (int m = 0; m < 4; ++m)
#pragma unroll
    for (int n = 0; n < 4; ++n)
#pragma unroll
      for (int r = 0; r < 4; ++r) acc[m][n][r] += bb[n];

  if (MODE == 1) {
    const int which = colBase >> 10;            // block-uniform: 0=q 1=k 2=v
    if (which < 2) {
      const float* gp = (which == 0) ? qg : kg;
      const float* bp = (which == 0) ? qb : kb;
      const float sc = (which == 0) ? 0.1803368801111204f : 1.0f;  // 0.125*log2(e)
      float gam[4], bet[4];
#pragma unroll
      for (int n = 0; n < 4; ++n) { gam[n] = gp[n * 16 + lr]; bet[n] = bp[n * 16 + lr]; }
#pragma unroll
      for (int m = 0; m < 4; ++m)
#pragma unroll
        for (int r = 0; r < 4; ++r) {
          float s1 = 0.f, s2 = 0.f;
#pragma unroll
          for (int n = 0; n < 4; ++n) {
            const float v = acc[m][n][r];
            s1 += v; s2 += v * v;
          }
#pragma unroll
          for (int off = 1; off < 16; off <<= 1) {
            s1 += __shfl_xor(s1, off);
            s2 += __shfl_xor(s2, off);
          }
          const float mu = s1 * 0.015625f;
          const float rs = rsqrtf(s2 * 0.015625f - mu * mu + 1e-5f);
#pragma unroll
          for (int n = 0; n < 4; ++n)
            acc[m][n][r] = ((acc[m][n][r] - mu) * rs * gam[n] + bet[n]) * sc;
        }
    }
  }

#pragma unroll
  for (int m = 0; m < 4; ++m) {
#pragma unroll
    for (int n = 0; n < 4; ++n) {
      const int gc = gc0 + n * 16;
#pragma unroll
      for (int r = 0; r < 4; ++r) {
        const int gr = gr0 + m * 16 + r;
        const float v = acc[m][n][r];
        if (MODE == 0) {
          Cf[(size_t)gr * N + gc] = v;
        } else {
          const int which = gc >> 10, e = gc & 1023;
          const int hh = e >> 6, d = e & 63;
          const int bidx = gr >> 11, t = gr & 2047;
          const int bh = bidx * Hn + hh;
          if (which == 0) {
            qo[((size_t)bh * Tn + t) * Dh + d] = f2b(v);
          } else if (which == 1) {
            ko2[((size_t)bh * Tn + t) * Dh + d] = f2b(v);
          } else {
            vo[((size_t)bh * Dh + d) * Tn + t] = f2b(v);   // transposed [bh][d][t]
          }
        }
      }
    }
  }
}

// ---------------- Flash attention (round-8 proven structure) ----------------
// 1024 blocks (XCD-swizzled), 4 waves, 32 q-rows/wave, KVBLK=64.
// Single change vs round 8: the per-tile __syncthreads() moved from loop end
// to right after the bv reads (last touch of shared K/V buffers). Correct:
// (a) barrier still separates all waves' buffer-cur reads from next-iter
// STAGE writes into cur; (b) the vmcnt(0) drain at the barrier still orders
// this iter's STAGE(cur^1) before next-iter bk reads; (c) everything after
// the barrier (P phases) is per-wave-private LDS + registers. Effect: the
// exp2/P/PV tail leaves the inter-wave critical path (waves desync -> role
// diversity for setprio).
__global__ __launch_bounds__(256) void flash_kernel(
    const short* __restrict__ qp, const short* __restrict__ kp,
    const short* __restrict__ vt, short* __restrict__ y) {
  __shared__ short Ks[2][4096];   // [buf][64 keys][64 d]
  __shared__ short Vs[2][4096];   // [buf][64 d][64 keys]
  __shared__ short Ps[4096];      // per-wave 1024 shorts: [32 q][32 k] half-tile
  const int tid = threadIdx.x, lane = tid & 63, w = tid >> 6;
  const int lr = lane & 15, lg = lane >> 4;

  // XCD swizzle (bijective): XCD x handles bh in [8x,8x+8), 16 q-tiles each
  const int j0 = blockIdx.x;
  const int xcd = j0 & 7, kk0 = j0 >> 3;
  const int bh = 8 * xcd + (kk0 & 7), qt = kk0 >> 3;

  const int qrow0 = qt * 128 + w * 32;
  const short* qbase = qp + ((size_t)bh * Tn + qrow0) * Dh;

  short8 aq[2][2];
#pragma unroll
  for (int m = 0; m < 2; ++m)
#pragma unroll
    for (int kk = 0; kk < 2; ++kk)
      aq[m][kk] = *(const short8*)&qbase[(m*16 + lr)*64 + kk*32 + lg*8];

  short8 ones;
#pragma unroll
  for (int i = 0; i < 8; ++i) ones[i] = (short)0x3F80;   // bf16 1.0

  f32x4 o[2][4] = {};
  f32x4 lacc[2] = {};             // row sums via ones-MFMA (C-layout = mrow layout)
  float mrow[2][4];
#pragma unroll
  for (int m = 0; m < 2; ++m)
#pragma unroll
    for (int r = 0; r < 4; ++r) mrow[m][r] = -3e38f;

  const int srow = tid >> 3;         // 0..31
  const int sc = (tid & 7) * 8;      // shorts
  short* Pw = Ps + w * 1024;
  const short* kb = kp + (size_t)bh * Tn * Dh;
  const short* vb = vt + (size_t)bh * Dh * Tn;

#define STAGE(jt, bsel)                                                   \
  {                                                                       \
    _Pragma("unroll")                                                     \
    for (int i = 0; i < 2; ++i) {                                         \
      const int row = i * 32 + srow;                                      \
      const int scs = sc ^ ((row & 7) << 3);                              \
      gload16(kb + (size_t)((jt) * 64 + row) * Dh + scs,                  \
              &Ks[bsel][w * 512 + i * 2048]);                             \
      gload16(vb + (size_t)row * Tn + (jt) * 64 + scs,                    \
              &Vs[bsel][w * 512 + i * 2048]);                             \
    }                                                                     \
  }

// P swizzle: 8-short granular, bijective within a 32-short row
#define PSW(q) ((((q) & 3) << 3) ^ (((q) & 4) << 2))

  STAGE(0, 0);
  __syncthreads();

  for (int j = 0; j < Tn / 64; ++j) {
    const int cur = j & 1;
    if (j + 1 < Tn / 64) STAGE(j + 1, cur ^ 1);

    // S = Q K^T  (C: row=q=lg*4+r+16m, col=key=lr+16n)
    short8 bk[4][2];
#pragma unroll
    for (int n = 0; n < 4; ++n)
#pragma unroll
      for (int kk = 0; kk < 2; ++kk) {
        const int row = n * 16 + lr;
        bk[n][kk] = *(const short8*)&Ks[cur][row*64 + ((kk*32 + lg*8) ^ ((row & 7) << 3))];
      }
    f32x4 s[2][4] = {};
    __builtin_amdgcn_s_setprio(1);
#pragma unroll
    for (int m = 0; m < 2; ++m)
#pragma unroll
      for (int n = 0; n < 4; ++n) {
        s[m][n] = mfma16(aq[m][0], bk[n][0], s[m][n]);
        s[m][n] = mfma16(aq[m][1], bk[n][1], s[m][n]);
      }
    __builtin_amdgcn_s_setprio(0);

    // defer-max: per-lane partial max vs stale row max
    float pm[2][4];
#pragma unroll
    for (int m = 0; m < 2; ++m)
#pragma unroll
      for (int r = 0; r < 4; ++r)
        pm[m][r] = fmaxf(fmaxf(s[m][0][r], s[m][1][r]), fmaxf(s[m][2][r], s[m][3][r]));
    int ok = 1;
#pragma unroll
    for (int m = 0; m < 2; ++m)
#pragma unroll
      for (int r = 0; r < 4; ++r)
        ok &= (pm[m][r] <= mrow[m][r] + 11.0f) ? 1 : 0;
    if (!__all(ok)) {
      float tm[2][4];
#pragma unroll
      for (int m = 0; m < 2; ++m)
#pragma unroll
        for (int r = 0; r < 4; ++r) tm[m][r] = pm[m][r];
#pragma unroll
      for (int off = 1; off < 16; off <<= 1)
#pragma unroll
        for (int m = 0; m < 2; ++m)
#pragma unroll
          for (int r = 0; r < 4; ++r)
            tm[m][r] = fmaxf(tm[m][r], __shfl_xor(tm[m][r], off));
#pragma unroll
      for (int m = 0; m < 2; ++m)
#pragma unroll
        for (int r = 0; r < 4; ++r) {
          const float mn = fmaxf(mrow[m][r], tm[m][r]);
          const float corr = __builtin_amdgcn_exp2f(mrow[m][r] - mn);
          lacc[m][r] *= corr;
#pragma unroll
          for (int dn = 0; dn < 4; ++dn) o[m][dn][r] *= corr;
          mrow[m][r] = mn;
        }
    }

    // V fragments (last reads of the shared cur buffers)
    short8 bv[4][2];
#pragma unroll
    for (int dn = 0; dn < 4; ++dn)
#pragma unroll
      for (int kk = 0; kk < 2; ++kk) {
        const int row = dn * 16 + lr;
        bv[dn][kk] = *(const short8*)&Vs[cur][row*64 + ((kk*32 + lg*8) ^ ((row & 7) << 3))];
      }

    // barrier here (not at loop end): all shared-buffer reads done; the
    // P/exp2/PV tail below is per-wave private and off the critical path
    __syncthreads();

    // ---- phase 0: keys 0..31 (n=0,1) ----
#pragma unroll
    for (int m = 0; m < 2; ++m)
#pragma unroll
      for (int n = 0; n < 2; ++n)
#pragma unroll
        for (int r = 0; r < 4; ++r) {
          const float p = __builtin_amdgcn_exp2f(s[m][n][r] - mrow[m][r]);
          const unsigned u = __builtin_bit_cast(unsigned, p);
          const int q = m*16 + lg*4 + r;
          Pw[q*32 + ((n*16 + lr) ^ PSW(q))] = (short)(u >> 16);
        }
    short8 pa0[2];
#pragma unroll
    for (int m = 0; m < 2; ++m) {
      const int q = m*16 + lr;
      pa0[m] = *(const short8*)&Pw[q*32 + ((lg*8) ^ PSW(q))];
    }
    __builtin_amdgcn_s_setprio(1);
#pragma unroll
    for (int m = 0; m < 2; ++m) {
      lacc[m] = mfma16(pa0[m], ones, lacc[m]);
#pragma unroll
      for (int dn = 0; dn < 4; ++dn)
        o[m][dn] = mfma16(pa0[m], bv[dn][0], o[m][dn]);
    }
    __builtin_amdgcn_s_setprio(0);

    // ---- phase 1: keys 32..63 (n=2,3), same buffer (in-order DS) ----
#pragma unroll
    for (int m = 0; m < 2; ++m)
#pragma unroll
      for (int n = 0; n < 2; ++n)
#pragma unroll
        for (int r = 0; r < 4; ++r) {
          const float p = __builtin_amdgcn_exp2f(s[m][2 + n][r] - mrow[m][r]);
          const unsigned u = __builtin_bit_cast(unsigned, p);
          const int q = m*16 + lg*4 + r;
          Pw[q*32 + ((n*16 + lr) ^ PSW(q))] = (short)(u >> 16);
        }
    short8 pa1[2];
#pragma unroll
    for (int m = 0; m < 2; ++m) {
      const int q = m*16 + lr;
      pa1[m] = *(const short8*)&Pw[q*32 + ((lg*8) ^ PSW(q))];
    }
    __builtin_amdgcn_s_setprio(1);
#pragma unroll
    for (int m = 0; m < 2; ++m) {
      lacc[m] = mfma16(pa1[m], ones, lacc[m]);
#pragma unroll
      for (int dn = 0; dn < 4; ++dn)
        o[m][dn] = mfma16(pa1[m], bv[dn][1], o[m][dn]);
    }
    __builtin_amdgcn_s_setprio(0);
  }
#undef STAGE
#undef PSW

  // normalize + store y[B][T][E] bf16 (lacc already holds full row sums)
  const int b = bh >> 4, hh = bh & 15;
  short* yb = y + (size_t)b * Tn * En + hh * 64;
#pragma unroll
  for (int m = 0; m < 2; ++m)
#pragma unroll
    for (int r = 0; r < 4; ++r) {
      const float rl = 1.0f / lacc[m][r];
      const int t = qrow0 + m*16 + lg*4 + r;
#pragma unroll
      for (int dn = 0; dn < 4; ++dn) {
        const int d = dn*16 + lr;
        yb[(size_t)t * En + d] = f2b(o[m][dn][r] * rl);
      }
    }
}

extern "C" void kernel_launch(void* const* d_in, const int* in_sizes, int n_in,
                              void* d_out, int out_size, void* d_ws, size_t ws_size,
                              hipStream_t stream) {
  const float* x     = (const float*)d_in[0];
  const float* Wqkv  = (const float*)d_in[1];
  const float* bqkv  = (const float*)d_in[2];
  const float* qg    = (const float*)d_in[3];
  const float* qb    = (const float*)d_in[4];
  const float* kg    = (const float*)d_in[5];
  const float* kb    = (const float*)d_in[6];
  const float* Wproj = (const float*)d_in[7];
  const float* bproj = (const float*)d_in[8];
  float* out = (float*)d_out;

  char* p = (char*)d_ws;
  short* xb     = (short*)p; p += (size_t)Mn * Kn * 2;
  short* wqkvT  = (short*)p; p += (size_t)N1 * Kn * 2;
  short* wprojT = (short*)p; p += (size_t)En * Kn * 2;
  short* qp     = (short*)p; p += (size_t)Mn * Kn * 2;
  short* kp     = (short*)p; p += (size_t)Mn * Kn * 2;
  short* vtb    = (short*)p; p += (size_t)Mn * Kn * 2;
  short* yb     = (short*)p; p += (size_t)Mn * Kn * 2;

  cvt_x_kernel<<<Mn * Kn / (256 * 8), 256, 0, stream>>>(x, xb);
  transpose_w_kernel<<<dim3(N1 / 32, Kn / 32), 256, 0, stream>>>(Wqkv, wqkvT, Kn, N1);
  transpose_w_kernel<<<dim3(En / 32, Kn / 32), 256, 0, stream>>>(Wproj, wprojT, Kn, En);
  gemm_kernel<1><<<(N1 / 128) * (Mn / 128), 256, 0, stream>>>(
      xb, wqkvT, bqkv, nullptr, qp, kp, vtb, qg, qb, kg, kb,
      N1, N1 / 128, (N1 / 128) * (Mn / 128) / 8);
  flash_kernel<<<1024, 256, 0, stream>>>(qp, kp, vtb, yb);
  gemm_kernel<0><<<(En / 128) * (Mn / 128), 256, 0, stream>>>(
      yb, wprojT, bproj, out, nullptr, nullptr, nullptr, nullptr, nullptr, nullptr, nullptr,
      En, En / 128, (En / 128) * (Mn / 128) / 8);
}

// Round 13
// 245.604 us; speedup vs baseline: 1.7757x; 1.0770x over previous
//
#include <hip/hip_runtime.h>

// Problem constants
#define Hn  16
#define Dh  64
#define Bb  4
#define Tn  2048
#define En  1024
#define Mn  8192           // B*T
#define N1  3072           // 3*E
#define Kn  1024           // E

typedef __attribute__((ext_vector_type(8)))  short  short8;
typedef __attribute__((ext_vector_type(4)))  short  short4v;
typedef __attribute__((ext_vector_type(4)))  float  f32x4;
typedef __attribute__((ext_vector_type(8)))  __bf16 bf16x8;

__device__ __forceinline__ float b2f(short s) {
  unsigned u = ((unsigned)(unsigned short)s) << 16;
  return __builtin_bit_cast(float, u);
}
__device__ __forceinline__ short f2b(float f) {
  unsigned u = __builtin_bit_cast(unsigned, f);
  u += 0x7fffu + ((u >> 16) & 1u);
  return (short)(u >> 16);
}
__device__ __forceinline__ f32x4 mfma16(short8 a, short8 b, f32x4 c) {
  return __builtin_amdgcn_mfma_f32_16x16x32_bf16(
      __builtin_bit_cast(bf16x8, a), __builtin_bit_cast(bf16x8, b), c, 0, 0, 0);
}
__device__ __forceinline__ void gload16(const void* g, void* l) {
  __builtin_amdgcn_global_load_lds(
      (const __attribute__((address_space(1))) unsigned int*)g,
      (__attribute__((address_space(3))) unsigned int*)l, 16, 0, 0);
}

// ---------------- merged preprocessing: cvt_x + transpose both W ----------------
// grid = 4096 (cvt) + 3072 (Wqkv^T) + 1024 (Wproj^T) = 8192 blocks
__global__ __launch_bounds__(256) void prep_kernel(
    const float* __restrict__ x, short* __restrict__ xb,
    const float* __restrict__ Wqkv, short* __restrict__ wqkvT,
    const float* __restrict__ Wproj, short* __restrict__ wprojT) {
  __shared__ float tile[32][33];
  const int bid = blockIdx.x, tid = threadIdx.x;
  if (bid < 4096) {
    const size_t i = ((size_t)bid * 256 + tid) * 8;
    f32x4 a = *(const f32x4*)&x[i];
    f32x4 b = *(const f32x4*)&x[i + 4];
    short8 o;
    o[0]=f2b(a[0]); o[1]=f2b(a[1]); o[2]=f2b(a[2]); o[3]=f2b(a[3]);
    o[4]=f2b(b[0]); o[5]=f2b(b[1]); o[6]=f2b(b[2]); o[7]=f2b(b[3]);
    *(short8*)&xb[i] = o;
    return;
  }
  const float* in; short* out; int R, C, bx, by;
  if (bid < 4096 + 3072) {
    const int b2 = bid - 4096;
    in = Wqkv; out = wqkvT; R = Kn; C = N1; bx = b2 % 96; by = b2 / 96;
  } else {
    const int b3 = bid - 7168;
    in = Wproj; out = wprojT; R = Kn; C = En; bx = b3 % 32; by = b3 / 32;
  }
  const int c0 = bx * 32, r0 = by * 32;
  const int lr = tid >> 3, lc = (tid & 7) * 4;
  f32x4 v = *(const f32x4*)&in[(size_t)(r0 + lr) * C + c0 + lc];
  tile[lr][lc] = v[0]; tile[lr][lc+1] = v[1]; tile[lr][lc+2] = v[2]; tile[lr][lc+3] = v[3];
  __syncthreads();
  const int oc = tid >> 3, orr = (tid & 7) * 4;
  short4v ov;
  ov[0] = f2b(tile[orr][oc]);   ov[1] = f2b(tile[orr+1][oc]);
  ov[2] = f2b(tile[orr+2][oc]); ov[3] = f2b(tile[orr+3][oc]);
  *(short4v*)&out[(size_t)(c0 + oc) * R + r0 + orr] = ov;
}

// ---------------- GEMM: C[M][N] = A[M][K] * Bt[N][K]^T + bias ----------------
// 1-D grid, bijective XCD swizzle. MODE 1: fused bias + q/k LayerNorm
// (q scaled 0.125*log2e) + COALESCED epilogue: each wave restages its 64x64
// output tile through its private 4KB LDS slice (2 rounds, XOR-swizzled) and
// issues 8 coalesced 16B stores/thread (q/k row-major; V transposed [bh][d][t])
// instead of 64 scalar 2B scatters. MODE 0: fp32 out + bias (unchanged).
template<int MODE>
__global__ __launch_bounds__(256) void gemm_kernel(
    const short* __restrict__ A, const short* __restrict__ Bt,
    const float* __restrict__ bias, float* __restrict__ Cf,
    short* __restrict__ qo, short* __restrict__ ko2, short* __restrict__ vo,
    const float* __restrict__ qg, const float* __restrict__ qb,
    const float* __restrict__ kg, const float* __restrict__ kb,
    int N, int NBX, int cpx) {
  __shared__ short S[8192];      // A half [0,4096) | B half [4096,8192)
  const int lin = blockIdx.x;
  const int swz = (lin & 7) * cpx + (lin >> 3);
  const int bx = swz % NBX, by = swz / NBX;
  const int tid = threadIdx.x, lane = tid & 63, w = tid >> 6;
  const int rowBase = by * 128, colBase = bx * 128;
  f32x4 acc[4][4] = {};
  const int srow = tid >> 2, sk = (tid & 3) << 3;
  const short* Ag = A  + (size_t)(rowBase + srow) * Kn + sk;
  const short* Bg = Bt + (size_t)(colBase + srow) * Kn + sk;
  short* AsW = S + w * 512;
  short* BsW = S + 4096 + w * 512;
  const int ar = (w >> 1) * 64, bc = (w & 1) * 64;
  const int lg = lane >> 4, lg8 = lg * 8, lr = lane & 15;

  for (int kt = 0; kt < Kn; kt += 32) {
    __syncthreads();
    gload16(Ag + kt,            AsW);
    gload16(Ag + kt + 64 * Kn,  AsW + 2048);
    gload16(Bg + kt,            BsW);
    gload16(Bg + kt + 64 * Kn,  BsW + 2048);
    __syncthreads();
    short8 af[4], bfr[4];
#pragma unroll
    for (int m = 0; m < 4; ++m) af[m]  = *(const short8*)&S[(ar + m*16 + lr)*32 + lg8];
#pragma unroll
    for (int n = 0; n < 4; ++n) bfr[n] = *(const short8*)&S[4096 + (bc + n*16 + lr)*32 + lg8];
#pragma unroll
    for (int m = 0; m < 4; ++m)
#pragma unroll
      for (int n = 0; n < 4; ++n)
        acc[m][n] = mfma16(af[m], bfr[n], acc[m][n]);
  }

  const int gr0 = rowBase + ar + lg * 4;
  const int gc0 = colBase + bc + lr;

  float bb[4];
#pragma unroll
  for (int n = 0; n < 4; ++n) bb[n] = bias[gc0 + n * 16];
#pragma unroll
  for (int m = 0; m < 4; ++m)
#pragma unroll
    for (int n = 0; n < 4; ++n)
#pragma unroll
      for (int r = 0; r < 4; ++r) acc[m][n][r] += bb[n];

  if (MODE == 0) {
#pragma unroll
    for (int m = 0; m < 4; ++m)
#pragma unroll
      for (int n = 0; n < 4; ++n) {
        const int gc = gc0 + n * 16;
#pragma unroll
        for (int r = 0; r < 4; ++r)
          Cf[(size_t)(gr0 + m*16 + r) * N + gc] = acc[m][n][r];
      }
    return;
  }

  // -------- MODE 1: fused LN + coalesced epilogue --------
  const int which = colBase >> 10;            // block-uniform: 0=q 1=k 2=v
  if (which < 2) {
    const float* gp = (which == 0) ? qg : kg;
    const float* bp = (which == 0) ? qb : kb;
    const float sc = (which == 0) ? 0.1803368801111204f : 1.0f;  // 0.125*log2(e)
    float gam[4], bet[4];
#pragma unroll
    for (int n = 0; n < 4; ++n) { gam[n] = gp[n * 16 + lr]; bet[n] = bp[n * 16 + lr]; }
#pragma unroll
    for (int m = 0; m < 4; ++m)
#pragma unroll
      for (int r = 0; r < 4; ++r) {
        float s1 = 0.f, s2 = 0.f;
#pragma unroll
        for (int n = 0; n < 4; ++n) {
          const float v = acc[m][n][r];
          s1 += v; s2 += v * v;
        }
#pragma unroll
        for (int off = 1; off < 16; off <<= 1) {
          s1 += __shfl_xor(s1, off);
          s2 += __shfl_xor(s2, off);
        }
        const float mu = s1 * 0.015625f;
        const float rs = rsqrtf(s2 * 0.015625f - mu * mu + 1e-5f);
#pragma unroll
        for (int n = 0; n < 4; ++n)
          acc[m][n][r] = ((acc[m][n][r] - mu) * rs * gam[n] + bet[n]) * sc;
      }
  }

  // other waves may still read S in their last MFMA
  __syncthreads();
  short* Sw = S + w * 2048;                   // per-wave private 4KB
  const int t0 = (rowBase & 2047) + ar;       // wave's first t (64 rows)
  const int bidx = (rowBase + ar) >> 11;
  const int hh = ((colBase + bc) & 1023) >> 6;
  const int bh = bidx * Hn + hh;
  const int l8 = lane & 7, ld8 = lane >> 3;

  if (which < 2) {
    short* dst0 = (which == 0) ? qo : ko2;
    // rounds over row halves; stage [32 t][64 d], 128B rows, swz=(t&7)<<3
#pragma unroll
    for (int p = 0; p < 2; ++p) {
#pragma unroll
      for (int mm = 0; mm < 2; ++mm) {
        const int m = p * 2 + mm;
#pragma unroll
        for (int n = 0; n < 4; ++n)
#pragma unroll
          for (int r = 0; r < 4; ++r) {
            const int tl = mm*16 + lg*4 + r;
            const int dl = n*16 + lr;
            Sw[tl*64 + (dl ^ ((tl & 7) << 3))] = f2b(acc[m][n][r]);
          }
      }
      // readback: instr i covers 8 rows x 128B = 1KB contiguous global
#pragma unroll
      for (int i = 0; i < 4; ++i) {
        const int tl = i*8 + ld8;
        short8 v = *(const short8*)&Sw[tl*64 + ((l8*8) ^ ((tl & 7) << 3))];
        const int t = t0 + p*32 + tl;
        *(short8*)&dst0[((size_t)bh * Tn + t) * Dh + l8*8] = v;
      }
    }
  } else {
    // V: rounds over d halves; stage [32 d][64 t], 128B rows, swz=(d&7)<<3
#pragma unroll
    for (int p = 0; p < 2; ++p) {
#pragma unroll
      for (int nn = 0; nn < 2; ++nn) {
        const int n = p * 2 + nn;
#pragma unroll
        for (int m = 0; m < 4; ++m)
#pragma unroll
          for (int r = 0; r < 4; ++r) {
            const int dl = nn*16 + lr;
            const int tc = m*16 + lg*4 + r;
            Sw[dl*64 + (tc ^ ((dl & 7) << 3))] = f2b(acc[m][n][r]);
          }
      }
#pragma unroll
      for (int i = 0; i < 4; ++i) {
        const int dl = i*8 + ld8;
        short8 v = *(const short8*)&Sw[dl*64 + ((l8*8) ^ ((dl & 7) << 3))];
        const int d = p*32 + dl;
        *(short8*)&vo[((size_t)bh * Dh + d) * Tn + t0 + l8*8] = v;
      }
    }
  }
}

// ---------------- Flash attention (round-8/12 proven; byte-identical) ----------------
__global__ __launch_bounds__(256) void flash_kernel(
    const short* __restrict__ qp, const short* __restrict__ kp,
    const short* __restrict__ vt, short* __restrict__ y) {
  __shared__ short Ks[2][4096];   // [buf][64 keys][64 d]
  __shared__ short Vs[2][4096];   // [buf][64 d][64 keys]
  __shared__ short Ps[4096];      // per-wave 1024 shorts: [32 q][32 k] half-tile
  const int tid = threadIdx.x, lane = tid & 63, w = tid >> 6;
  const int lr = lane & 15, lg = lane >> 4;

  const int j0 = blockIdx.x;
  const int xcd = j0 & 7, kk0 = j0 >> 3;
  const int bh = 8 * xcd + (kk0 & 7), qt = kk0 >> 3;

  const int qrow0 = qt * 128 + w * 32;
  const short* qbase = qp + ((size_t)bh * Tn + qrow0) * Dh;

  short8 aq[2][2];
#pragma unroll
  for (int m = 0; m < 2; ++m)
#pragma unroll
    for (int kk = 0; kk < 2; ++kk)
      aq[m][kk] = *(const short8*)&qbase[(m*16 + lr)*64 + kk*32 + lg*8];

  short8 ones;
#pragma unroll
  for (int i = 0; i < 8; ++i) ones[i] = (short)0x3F80;   // bf16 1.0

  f32x4 o[2][4] = {};
  f32x4 lacc[2] = {};
  float mrow[2][4];
#pragma unroll
  for (int m = 0; m < 2; ++m)
#pragma unroll
    for (int r = 0; r < 4; ++r) mrow[m][r] = -3e38f;

  const int srow = tid >> 3;
  const int sc = (tid & 7) * 8;
  short* Pw = Ps + w * 1024;
  const short* kb = kp + (size_t)bh * Tn * Dh;
  const short* vb = vt + (size_t)bh * Dh * Tn;

#define STAGE(jt, bsel)                                                   \
  {                                                                       \
    _Pragma("unroll")                                                     \
    for (int i = 0; i < 2; ++i) {                                         \
      const int row = i * 32 + srow;                                      \
      const int scs = sc ^ ((row & 7) << 3);                              \
      gload16(kb + (size_t)((jt) * 64 + row) * Dh + scs,                  \
              &Ks[bsel][w * 512 + i * 2048]);                             \
      gload16(vb + (size_t)row * Tn + (jt) * 64 + scs,                    \
              &Vs[bsel][w * 512 + i * 2048]);                             \
    }                                                                     \
  }

#define PSW(q) ((((q) & 3) << 3) ^ (((q) & 4) << 2))

  STAGE(0, 0);
  __syncthreads();

  for (int j = 0; j < Tn / 64; ++j) {
    const int cur = j & 1;
    if (j + 1 < Tn / 64) STAGE(j + 1, cur ^ 1);

    short8 bk[4][2];
#pragma unroll
    for (int n = 0; n < 4; ++n)
#pragma unroll
      for (int kk = 0; kk < 2; ++kk) {
        const int row = n * 16 + lr;
        bk[n][kk] = *(const short8*)&Ks[cur][row*64 + ((kk*32 + lg*8) ^ ((row & 7) << 3))];
      }
    f32x4 s[2][4] = {};
    __builtin_amdgcn_s_setprio(1);
#pragma unroll
    for (int m = 0; m < 2; ++m)
#pragma unroll
      for (int n = 0; n < 4; ++n) {
        s[m][n] = mfma16(aq[m][0], bk[n][0], s[m][n]);
        s[m][n] = mfma16(aq[m][1], bk[n][1], s[m][n]);
      }
    __builtin_amdgcn_s_setprio(0);

    float pm[2][4];
#pragma unroll
    for (int m = 0; m < 2; ++m)
#pragma unroll
      for (int r = 0; r < 4; ++r)
        pm[m][r] = fmaxf(fmaxf(s[m][0][r], s[m][1][r]), fmaxf(s[m][2][r], s[m][3][r]));
    int ok = 1;
#pragma unroll
    for (int m = 0; m < 2; ++m)
#pragma unroll
      for (int r = 0; r < 4; ++r)
        ok &= (pm[m][r] <= mrow[m][r] + 11.0f) ? 1 : 0;
    if (!__all(ok)) {
      float tm[2][4];
#pragma unroll
      for (int m = 0; m < 2; ++m)
#pragma unroll
        for (int r = 0; r < 4; ++r) tm[m][r] = pm[m][r];
#pragma unroll
      for (int off = 1; off < 16; off <<= 1)
#pragma unroll
        for (int m = 0; m < 2; ++m)
#pragma unroll
          for (int r = 0; r < 4; ++r)
            tm[m][r] = fmaxf(tm[m][r], __shfl_xor(tm[m][r], off));
#pragma unroll
      for (int m = 0; m < 2; ++m)
#pragma unroll
        for (int r = 0; r < 4; ++r) {
          const float mn = fmaxf(mrow[m][r], tm[m][r]);
          const float corr = __builtin_amdgcn_exp2f(mrow[m][r] - mn);
          lacc[m][r] *= corr;
#pragma unroll
          for (int dn = 0; dn < 4; ++dn) o[m][dn][r] *= corr;
          mrow[m][r] = mn;
        }
    }

    short8 bv[4][2];
#pragma unroll
    for (int dn = 0; dn < 4; ++dn)
#pragma unroll
      for (int kk = 0; kk < 2; ++kk) {
        const int row = dn * 16 + lr;
        bv[dn][kk] = *(const short8*)&Vs[cur][row*64 + ((kk*32 + lg*8) ^ ((row & 7) << 3))];
      }

    __syncthreads();

#pragma unroll
    for (int m = 0; m < 2; ++m)
#pragma unroll
      for (int n = 0; n < 2; ++n)
#pragma unroll
        for (int r = 0; r < 4; ++r) {
          const float p = __builtin_amdgcn_exp2f(s[m][n][r] - mrow[m][r]);
          const unsigned u = __builtin_bit_cast(unsigned, p);
          const int q = m*16 + lg*4 + r;
          Pw[q*32 + ((n*16 + lr) ^ PSW(q))] = (short)(u >> 16);
        }
    short8 pa0[2];
#pragma unroll
    for (int m = 0; m < 2; ++m) {
      const int q = m*16 + lr;
      pa0[m] = *(const short8*)&Pw[q*32 + ((lg*8) ^ PSW(q))];
    }
    __builtin_amdgcn_s_setprio(1);
#pragma unroll
    for (int m = 0; m < 2; ++m) {
      lacc[m] = mfma16(pa0[m], ones, lacc[m]);
#pragma unroll
      for (int dn = 0; dn < 4; ++dn)
        o[m][dn] = mfma16(pa0[m], bv[dn][0], o[m][dn]);
    }
    __builtin_amdgcn_s_setprio(0);

#pragma unroll
    for (int m = 0; m < 2; ++m)
#pragma unroll
      for (int n = 0; n < 2; ++n)
#pragma unroll
        for (int r = 0; r < 4; ++r) {
          const float p = __builtin_amdgcn_exp2f(s[m][2 + n][r] - mrow[m][r]);
          const unsigned u = __builtin_bit_cast(unsigned, p);
          const int q = m*16 + lg*4 + r;
          Pw[q*32 + ((n*16 + lr) ^ PSW(q))] = (short)(u >> 16);
        }
    short8 pa1[2];
#pragma unroll
    for (int m = 0; m < 2; ++m) {
      const int q = m*16 + lr;
      pa1[m] = *(const short8*)&Pw[q*32 + ((lg*8) ^ PSW(q))];
    }
    __builtin_amdgcn_s_setprio(1);
#pragma unroll
    for (int m = 0; m < 2; ++m) {
      lacc[m] = mfma16(pa1[m], ones, lacc[m]);
#pragma unroll
      for (int dn = 0; dn < 4; ++dn)
        o[m][dn] = mfma16(pa1[m], bv[dn][1], o[m][dn]);
    }
    __builtin_amdgcn_s_setprio(0);
  }
#undef STAGE
#undef PSW

  const int b = bh >> 4, hh = bh & 15;
  short* yb = y + (size_t)b * Tn * En + hh * 64;
#pragma unroll
  for (int m = 0; m < 2; ++m)
#pragma unroll
    for (int r = 0; r < 4; ++r) {
      const float rl = 1.0f / lacc[m][r];
      const int t = qrow0 + m*16 + lg*4 + r;
#pragma unroll
      for (int dn = 0; dn < 4; ++dn) {
        const int d = dn*16 + lr;
        yb[(size_t)t * En + d] = f2b(o[m][dn][r] * rl);
      }
    }
}

extern "C" void kernel_launch(void* const* d_in, const int* in_sizes, int n_in,
                              void* d_out, int out_size, void* d_ws, size_t ws_size,
                              hipStream_t stream) {
  const float* x     = (const float*)d_in[0];
  const float* Wqkv  = (const float*)d_in[1];
  const float* bqkv  = (const float*)d_in[2];
  const float* qg    = (const float*)d_in[3];
  const float* qb    = (const float*)d_in[4];
  const float* kg    = (const float*)d_in[5];
  const float* kb    = (const float*)d_in[6];
  const float* Wproj = (const float*)d_in[7];
  const float* bproj = (const float*)d_in[8];
  float* out = (float*)d_out;

  char* p = (char*)d_ws;
  short* xb     = (short*)p; p += (size_t)Mn * Kn * 2;
  short* wqkvT  = (short*)p; p += (size_t)N1 * Kn * 2;
  short* wprojT = (short*)p; p += (size_t)En * Kn * 2;
  short* qp     = (short*)p; p += (size_t)Mn * Kn * 2;
  short* kp     = (short*)p; p += (size_t)Mn * Kn * 2;
  short* vtb    = (short*)p; p += (size_t)Mn * Kn * 2;
  short* yb     = (short*)p; p += (size_t)Mn * Kn * 2;

  prep_kernel<<<8192, 256, 0, stream>>>(x, xb, Wqkv, wqkvT, Wproj, wprojT);
  gemm_kernel<1><<<(N1 / 128) * (Mn / 128), 256, 0, stream>>>(
      xb, wqkvT, bqkv, nullptr, qp, kp, vtb, qg, qb, kg, kb,
      N1, N1 / 128, (N1 / 128) * (Mn / 128) / 8);
  flash_kernel<<<1024, 256, 0, stream>>>(qp, kp, vtb, yb);
  gemm_kernel<0><<<(En / 128) * (Mn / 128), 256, 0, stream>>>(
      yb, wprojT, bproj, out, nullptr, nullptr, nullptr, nullptr, nullptr, nullptr, nullptr,
      En, En / 128, (En / 128) * (Mn / 128) / 8);
}